// Round 5
// baseline (480.935 us; speedup 1.0000x reference)
//
#include <hip/hip_runtime.h>
#include <cstdint>

// ---------------------------------------------------------------------------
// Attention (Luong general): out = softmax(dec @ (enc@W)^T) @ enc
// B=8, S_enc=S_dec=2048, H=512, fp32 in/out.
//
// bf16 MFMA; split-precision (hi+lo bf16, 3-term) for the two matmuls feeding
// softmax; plain bf16 for PV.
// Round 7: measured round-4 LDS traffic = 120 B/cyc/CU (~94% of the 128 B/cyc
// hardware peak) -> logits GEMM is LDS-BANDWIDTH-bound, not schedule-bound.
// Fix: B operand direct global->register with a FULL TILE of prefetch slack
// (round-3 failed with ~0 slack), terms reordered (ah.bh, ah.bl, al.bh) so
// blc single-buffers and xah dies before xal -> no spill. LDS now A-planes
// only: 160 KB/tile (~1330 cyc) vs MFMA 930 cyc -> ~65% ceiling.
// Also: enc split+transpose fused (saves one 67 MB enc read).
// ---------------------------------------------------------------------------

#define DEVINL __device__ __forceinline__

typedef __attribute__((ext_vector_type(8))) short short8;
typedef __attribute__((ext_vector_type(4))) float f32x4;

DEVINL short f2bf(float x) {
    union { float f; uint32_t u; } v; v.f = x;
    uint32_t r = v.u + 0x7FFFu + ((v.u >> 16) & 1u);   // RNE
    return (short)(r >> 16);
}
DEVINL float bf2f(short h) {
    union { uint32_t u; float f; } v; v.u = ((uint32_t)(uint16_t)h) << 16;
    return v.f;
}

DEVINL void gload_lds16(const void* g, void* l) {
    __builtin_amdgcn_global_load_lds(
        (const __attribute__((address_space(1))) char*)g,
        (__attribute__((address_space(3))) char*)l, 16, 0, 0);
}

// ---------------------------------------------------------------------------
// split fp32 -> (hi, lo) bf16 arrays.  8 elems/thread, exact-cover grids.
// ---------------------------------------------------------------------------
__global__ __launch_bounds__(256)
void split_kernel(const float* __restrict__ x, short* __restrict__ hi,
                  short* __restrict__ lo)
{
    long i = ((long)blockIdx.x * 256 + threadIdx.x) * 8;
    f32x4 a = *(const f32x4*)(x + i);
    f32x4 b = *(const f32x4*)(x + i + 4);
    short8 h, l;
#pragma unroll
    for (int j = 0; j < 4; j++) {
        short ha = f2bf(a[j]); h[j] = ha;     l[j] = f2bf(a[j] - bf2f(ha));
        short hb = f2bf(b[j]); h[4 + j] = hb; l[4 + j] = f2bf(b[j] - bf2f(hb));
    }
    *(short8*)(hi + i) = h;
    *(short8*)(lo + i) = l;
}

// W[512k][512n] -> Wt_hi/lo[n][k]
__global__ __launch_bounds__(256)
void split_w_kernel(const float* __restrict__ w, short* __restrict__ wth,
                    short* __restrict__ wtl)
{
    int idx = blockIdx.x * 256 + threadIdx.x;   // k*512 + n
    int k = idx >> 9, n = idx & 511;
    float v = w[idx];
    short h = f2bf(v);
    wth[(long)n * 512 + k] = h;
    wtl[(long)n * 512 + k] = f2bf(v - bf2f(h));
}

// Fused: enc[b][s][e] fp32 -> enc_hi/enc_lo [b][s][e] bf16 + enc_t[b][e][s]
// bf16 (PV B-operand).  Reads enc exactly once.
__global__ __launch_bounds__(256)
void split_transpose_kernel(const float* __restrict__ x, short* __restrict__ hi,
                            short* __restrict__ lo, short* __restrict__ xt)
{
    __shared__ short tile[32][33];
    const int b  = blockIdx.z;
    const int s0 = blockIdx.x * 32;
    const int e0 = blockIdx.y * 32;
    const float* px = x + (long)b * 2048 * 512;
    short* ph = hi + (long)b * 2048 * 512;
    short* pl = lo + (long)b * 2048 * 512;
    short* pt = xt + (long)b * 512 * 2048;
    const int tx = threadIdx.x & 31;
    const int ty = threadIdx.x >> 5;   // 0..7
#pragma unroll
    for (int r = 0; r < 32; r += 8) {
        long idx = (long)(s0 + ty + r) * 512 + e0 + tx;
        float v = px[idx];
        short h = f2bf(v);
        ph[idx] = h;
        pl[idx] = f2bf(v - bf2f(h));
        tile[ty + r][tx] = h;
    }
    __syncthreads();
#pragma unroll
    for (int r = 0; r < 32; r += 8)
        pt[(long)(e0 + ty + r) * 2048 + s0 + tx] = tile[tx][ty + r];
}

// ---------------------------------------------------------------------------
// gemm_bt: C[m][n] = sum_k A[m][k]*B[n][k]  (both operands K-contiguous).
// 128x128 tile, BK=32, 4 waves (2x2 of 64x64), 16x16x32 bf16 MFMA.
// (kept for the enc@W projection and the PV matmul)
// ---------------------------------------------------------------------------
template<int NTERMS, bool SPLIT_OUT>
__global__ __launch_bounds__(256, 2)
void gemm_bt(const short* __restrict__ Ah, const short* __restrict__ Al,
             const short* __restrict__ Bh, const short* __restrict__ Bl,
             float* __restrict__ C, short* __restrict__ Ch, short* __restrict__ Cl,
             int K, int lda, int ldb, int ldc,
             long sA, long sB, long sC)
{
    extern __shared__ char smem_raw[];
    constexpr int OPS = (NTERMS == 3) ? 4 : 2;     // operand planes per set
    constexpr int SET = 128 * 32 * OPS;            // shorts per buffer set
    short* smem = (short*)smem_raw;                // 2 sets

    const int tid  = threadIdx.x;
    const int wave = tid >> 6;
    const int lane = tid & 63;
    const int quad = lane >> 4;
    const int l16  = lane & 15;
    const int wm   = (wave >> 1) * 64;
    const int wn   = (wave & 1) * 64;

    const long tile_m = (long)blockIdx.y * 128;
    const long tile_n = (long)blockIdx.x * 128;
    const int  bz     = blockIdx.z;

    const short* pAh = Ah + (long)bz * sA;
    const short* pBh = Bh + (long)bz * sB;
    const short* pAl = (NTERMS == 3) ? (Al + (long)bz * sA) : nullptr;
    const short* pBl = (NTERMS == 3) ? (Bl + (long)bz * sB) : nullptr;

    // staging: thread t -> row t>>2, k-subchunk (t&3)*8; LDS byte off = 16*t
    const int srow = tid >> 2;
    const int skq  = (tid & 3) * 8;
    const int lds_off = srow * 32 + skq;
    const long ga0 = (tile_m + srow) * (long)lda + skq;
    const long gb0 = (tile_n + srow) * (long)ldb + skq;

    auto stage = [&](int k0, int buf) {
        short* s   = smem + buf * SET;
        short* ash = s;
        short* bsh = s + 128 * 32;
        gload_lds16(pAh + ga0 + k0,             ash + lds_off);
        gload_lds16(pAh + ga0 + 64l * lda + k0, ash + lds_off + 64 * 32);
        gload_lds16(pBh + gb0 + k0,             bsh + lds_off);
        gload_lds16(pBh + gb0 + 64l * ldb + k0, bsh + lds_off + 64 * 32);
        if constexpr (NTERMS == 3) {
            short* asl = s + 2 * 128 * 32;
            short* bsl = s + 3 * 128 * 32;
            gload_lds16(pAl + ga0 + k0,             asl + lds_off);
            gload_lds16(pAl + ga0 + 64l * lda + k0, asl + lds_off + 64 * 32);
            gload_lds16(pBl + gb0 + k0,             bsl + lds_off);
            gload_lds16(pBl + gb0 + 64l * ldb + k0, bsl + lds_off + 64 * 32);
        }
    };

    f32x4 acc[4][4] = {};
    stage(0, 0);
    int cur = 0;

    for (int k0 = 0; k0 < K; k0 += 32) {
        __syncthreads();                    // drains vmcnt: stage(cur) done
        if (k0 + 32 < K) stage(k0 + 32, cur ^ 1);   // prefetch next tile

        short* s   = smem + cur * SET;
        short* ash = s;
        short* bsh = s + 128 * 32;
        short* asl = s + 2 * 128 * 32;
        short* bsl = s + 3 * 128 * 32;

        short8 ah[4], bh[4], al[4], bl[4];
#pragma unroll
        for (int i = 0; i < 4; i++) {
            ah[i] = *(const short8*)&ash[(wm + i * 16 + l16) * 32 + quad * 8];
            bh[i] = *(const short8*)&bsh[(wn + i * 16 + l16) * 32 + quad * 8];
            if constexpr (NTERMS == 3) {
                al[i] = *(const short8*)&asl[(wm + i * 16 + l16) * 32 + quad * 8];
                bl[i] = *(const short8*)&bsl[(wn + i * 16 + l16) * 32 + quad * 8];
            }
        }
#pragma unroll
        for (int i = 0; i < 4; i++)
#pragma unroll
            for (int j = 0; j < 4; j++) {
                acc[i][j] = __builtin_amdgcn_mfma_f32_16x16x32_bf16(ah[i], bh[j], acc[i][j], 0, 0, 0);
                if constexpr (NTERMS == 3) {
                    acc[i][j] = __builtin_amdgcn_mfma_f32_16x16x32_bf16(ah[i], bl[j], acc[i][j], 0, 0, 0);
                    acc[i][j] = __builtin_amdgcn_mfma_f32_16x16x32_bf16(al[i], bh[j], acc[i][j], 0, 0, 0);
                }
            }
        cur ^= 1;
    }

    // epilogue: D row = quad*4 + reg, col = lane&15  (m89-verified mapping)
#pragma unroll
    for (int i = 0; i < 4; i++)
#pragma unroll
        for (int j = 0; j < 4; j++) {
            const long row0 = tile_m + wm + i * 16 + quad * 4;
            const long col  = tile_n + wn + j * 16 + l16;
#pragma unroll
            for (int r = 0; r < 4; r++) {
                float v = acc[i][j][r];
                if constexpr (SPLIT_OUT) {
                    long idx = (long)bz * sC + (row0 + r) * (long)ldc + col;
                    short h = f2bf(v);
                    Ch[idx] = h;
                    Cl[idx] = f2bf(v - bf2f(h));
                } else {
                    C[(long)bz * sC + (row0 + r) * (long)ldc + col] = v;
                }
            }
        }
}

// ---------------------------------------------------------------------------
// gemm3_256: C[m][n] = sum_k A[m][k]*B[n][k], 3-term split bf16.
// 256x256 tile, BK=32, 8 waves (2x4 of 128x64), 16x16x32 bf16 MFMA.
//
// A (dec, 4-way wave reuse): LDS-staged, 2 planes (Ah,Al), double-buffered
//   = 64 KiB, swizzled source (0 bank conflicts, verified r3).
// B (ep, 2-way reuse): direct global->register short8 fragments, SAME data
//   layout the swizzled ds_read produced (B[row][quad*8..+8]).
//   bh double-buffered in regs, loaded at ph0 of tile t for t+1 (~6 phases
//   of slack; round-3's failure was ~0 slack). blc single-buffered: terms
//   run ah.bh (ph0/1), ah.bl (ph2/3, no LDS), al.bh (ph4/5), so blc is
//   dead after ph3 and reloaded there for t+1 (~5 phases slack).
// Per-tile LDS = 128 KB reads + 32 KB writes (was 260 KB) -> no longer at
// the 128 B/cyc LDS-bandwidth wall. vmem adds 64 KB/tile (43 B/cyc < L2).
// Counted vmcnt(4) at tile end keeps blc(t+1) in flight; never drains to 0.
// ---------------------------------------------------------------------------
__global__ __launch_bounds__(512, 2)
void gemm3_256(const short* __restrict__ Ah, const short* __restrict__ Al,
               const short* __restrict__ Bh, const short* __restrict__ Bl,
               float* __restrict__ C,
               int K, int lda, int ldb, int ldc,
               long sA, long sB, long sC, int nbx, int nby)
{
    extern __shared__ char smem_raw[];
    short* smem = (short*)smem_raw;
    constexpr int PL  = 256 * 32;          // 8192 shorts per plane (16 KiB)
    constexpr int SET = 2 * PL;            // Ah+Al planes per buffer set

    const int t    = threadIdx.x;
    const int wave = t >> 6;
    const int lane = t & 63;
    const int quad = lane >> 4;
    const int l16  = lane & 15;
    const int wm   = (wave >> 2) * 128;    // 2 wave-rows
    const int wn   = (wave & 3) * 64;      // 4 wave-cols
    const int kslot8 = ((quad ^ ((l16 >> 1) & 3)) << 3);

    // bijective XCD swizzle (gridDim.x % 8 == 0): one batch per XCD
    const int nwg = gridDim.x;
    const int wg  = blockIdx.x;
    const int swz = (wg & 7) * (nwg >> 3) + (wg >> 3);
    const int per_b = nbx * nby;
    const int bz  = swz / per_b;
    const int rem = swz - bz * per_b;
    const long tile_m = (long)(rem / nbx) * 256;
    const long tile_n = (long)(rem % nbx) * 256;

    const short* pAh = Ah + (long)bz * sA;
    const short* pAl = Al + (long)bz * sA;
    const short* pBh = Bh + (long)bz * sB;
    const short* pBl = Bl + (long)bz * sB;

    // A staging: thread t -> row t>>2 (half0) / +128 (half1), chunk slot t&3
    // holds global chunk (t&3) ^ ((row>>1)&3)  [read-side XOR matches]
    const int srow   = t >> 2;                       // 0..127
    const int schunk = (t & 3) ^ ((t >> 3) & 3);
    const long gA  = (tile_m + srow) * (long)lda + schunk * 8;
    const long gA2 = gA + 128l * lda;
    const int ld0 = t * 8;                           // shorts, linear dest

    // B direct-load offsets (shorts, fits int): row (wn+j*16+l16), chunk quad
    int gb[4];
#pragma unroll
    for (int j = 0; j < 4; j++)
        gb[j] = (int)((tile_n + wn + j * 16 + l16) * (long)ldb + quad * 8);

    f32x4 acc[8][4] = {};
    short8 bh0[4], bh1[4], blc[4];

    // ---- prologue: stage A(0), load bh(0), bl(0) ----
    {
        short* s = smem;
        gload_lds16(pAh + gA,  s + ld0);
        gload_lds16(pAh + gA2, s + ld0 + 4096);
        gload_lds16(pAl + gA,  s + PL + ld0);
        gload_lds16(pAl + gA2, s + PL + ld0 + 4096);
    }
#pragma unroll
    for (int j = 0; j < 4; j++) bh0[j] = *(const short8*)(pBh + gb[j]);
#pragma unroll
    for (int j = 0; j < 4; j++) blc[j] = *(const short8*)(pBl + gb[j]);
    asm volatile("s_waitcnt vmcnt(0)" ::: "memory");
    __builtin_amdgcn_s_barrier();

    auto run_tile = [&](int cur, short8 (&bhU)[4], short8 (&bhF)[4],
                        int k0n, bool more) {
        const short* sp   = smem + cur * SET;
        short* sn         = smem + (cur ^ 1) * SET;
        const short* ah_p = sp;
        const short* al_p = sp + PL;
        short8 xah[8], xal[4];

        // ---- phase 0: rd ah[0..3] | stage Ah(t+1) | load bh(t+1) | ah.bh ----
#pragma unroll
        for (int i = 0; i < 4; i++)
            xah[i] = *(const short8*)&ah_p[(wm + i * 16 + l16) * 32 + kslot8];
        if (more) {
            gload_lds16(pAh + gA  + k0n, sn + ld0);
            gload_lds16(pAh + gA2 + k0n, sn + ld0 + 4096);
#pragma unroll
            for (int j = 0; j < 4; j++)
                bhF[j] = *(const short8*)(pBh + gb[j] + k0n);
        }
        __builtin_amdgcn_s_barrier();
        asm volatile("s_waitcnt lgkmcnt(0)" ::: "memory");
        __builtin_amdgcn_sched_barrier(0);
        __builtin_amdgcn_s_setprio(1);
#pragma unroll
        for (int i = 0; i < 4; i++)
#pragma unroll
            for (int j = 0; j < 4; j++)
                acc[i][j] = __builtin_amdgcn_mfma_f32_16x16x32_bf16(xah[i], bhU[j], acc[i][j], 0, 0, 0);
        __builtin_amdgcn_s_setprio(0);
        __builtin_amdgcn_s_barrier();

        // ---- phase 1: rd ah[4..7] | stage Al(t+1) | ah.bh ----
#pragma unroll
        for (int i = 0; i < 4; i++)
            xah[4 + i] = *(const short8*)&ah_p[(wm + 64 + i * 16 + l16) * 32 + kslot8];
        if (more) {
            gload_lds16(pAl + gA  + k0n, sn + PL + ld0);
            gload_lds16(pAl + gA2 + k0n, sn + PL + ld0 + 4096);
        }
        __builtin_amdgcn_s_barrier();
        asm volatile("s_waitcnt lgkmcnt(0)" ::: "memory");
        __builtin_amdgcn_sched_barrier(0);
        __builtin_amdgcn_s_setprio(1);
#pragma unroll
        for (int i = 0; i < 4; i++)
#pragma unroll
            for (int j = 0; j < 4; j++)
                acc[4 + i][j] = __builtin_amdgcn_mfma_f32_16x16x32_bf16(xah[4 + i], bhU[j], acc[4 + i][j], 0, 0, 0);
        __builtin_amdgcn_s_setprio(0);
        __builtin_amdgcn_s_barrier();

        // ---- phases 2+3 (merged, no LDS): ah.bl, then reload blc(t+1) ----
        __builtin_amdgcn_s_setprio(1);
#pragma unroll
        for (int i = 0; i < 8; i++)
#pragma unroll
            for (int j = 0; j < 4; j++)
                acc[i][j] = __builtin_amdgcn_mfma_f32_16x16x32_bf16(xah[i], blc[j], acc[i][j], 0, 0, 0);
        __builtin_amdgcn_s_setprio(0);
        if (more) {
#pragma unroll
            for (int j = 0; j < 4; j++)
                blc[j] = *(const short8*)(pBl + gb[j] + k0n);
        }

        // ---- phase 4: rd al[0..3] | al.bh ----
#pragma unroll
        for (int i = 0; i < 4; i++)
            xal[i] = *(const short8*)&al_p[(wm + i * 16 + l16) * 32 + kslot8];
        __builtin_amdgcn_s_barrier();
        asm volatile("s_waitcnt lgkmcnt(0)" ::: "memory");
        __builtin_amdgcn_sched_barrier(0);
        __builtin_amdgcn_s_setprio(1);
#pragma unroll
        for (int i = 0; i < 4; i++)
#pragma unroll
            for (int j = 0; j < 4; j++)
                acc[i][j] = __builtin_amdgcn_mfma_f32_16x16x32_bf16(xal[i], bhU[j], acc[i][j], 0, 0, 0);
        __builtin_amdgcn_s_setprio(0);
        __builtin_amdgcn_s_barrier();

        // ---- phase 5: rd al[4..7] | al.bh | counted drain ----
#pragma unroll
        for (int i = 0; i < 4; i++)
            xal[i] = *(const short8*)&al_p[(wm + 64 + i * 16 + l16) * 32 + kslot8];
        __builtin_amdgcn_s_barrier();
        asm volatile("s_waitcnt lgkmcnt(0)" ::: "memory");
        __builtin_amdgcn_sched_barrier(0);
        __builtin_amdgcn_s_setprio(1);
#pragma unroll
        for (int i = 0; i < 4; i++)
#pragma unroll
            for (int j = 0; j < 4; j++)
                acc[4 + i][j] = __builtin_amdgcn_mfma_f32_16x16x32_bf16(xal[i], bhU[j], acc[4 + i][j], 0, 0, 0);
        __builtin_amdgcn_s_setprio(0);
        if (more)   // drain stages+bhF (8 older); keep blc(t+1) (4 newest)
            asm volatile("s_waitcnt vmcnt(4)" ::: "memory");
        __builtin_amdgcn_s_barrier();
    };

    const int NT = K >> 5;      // 16
#pragma unroll 1
    for (int kt = 0; kt < NT; kt += 2) {
        run_tile(0, bh0, bh1, (kt + 1) << 5, kt + 1 < NT);
        run_tile(1, bh1, bh0, (kt + 2) << 5, kt + 2 < NT);
    }

    // epilogue: D row = quad*4 + reg, col = lane&15  (m89-verified mapping)
#pragma unroll
    for (int i = 0; i < 8; i++)
#pragma unroll
        for (int j = 0; j < 4; j++) {
            const long row0 = tile_m + wm + i * 16 + quad * 4;
            const long col  = tile_n + wn + j * 16 + l16;
#pragma unroll
            for (int r = 0; r < 4; r++)
                C[(long)bz * sC + (row0 + r) * (long)ldc + col] = acc[i][j][r];
        }
}

// ---------------------------------------------------------------------------
// Row softmax over 2048 fp32 logits; writes P as contiguous bf16.
// ---------------------------------------------------------------------------
__global__ __launch_bounds__(256)
void softmax_kernel(const float* __restrict__ logits, short* __restrict__ P)
{
    const long row = blockIdx.x;
    const float* p = logits + row * 2048;
    const int tid = threadIdx.x;
    const int lane = tid & 63, wave = tid >> 6;

    f32x4 v0 = *(const f32x4*)(p + tid * 8);
    f32x4 v1 = *(const f32x4*)(p + tid * 8 + 4);

    float m = fmaxf(fmaxf(fmaxf(v0[0], v0[1]), fmaxf(v0[2], v0[3])),
                    fmaxf(fmaxf(v1[0], v1[1]), fmaxf(v1[2], v1[3])));
#pragma unroll
    for (int o = 32; o > 0; o >>= 1) m = fmaxf(m, __shfl_xor(m, o));

    __shared__ float red[8];
    if (lane == 0) red[wave] = m;
    __syncthreads();
    m = fmaxf(fmaxf(red[0], red[1]), fmaxf(red[2], red[3]));

    float e[8];
    float s = 0.f;
#pragma unroll
    for (int i = 0; i < 4; i++) { e[i] = __expf(v0[i] - m); s += e[i]; }
#pragma unroll
    for (int i = 0; i < 4; i++) { e[4 + i] = __expf(v1[i] - m); s += e[4 + i]; }
#pragma unroll
    for (int o = 32; o > 0; o >>= 1) s += __shfl_xor(s, o);
    if (lane == 0) red[4 + wave] = s;
    __syncthreads();
    const float inv = 1.f / (red[4] + red[5] + red[6] + red[7]);

    short8 ob;
#pragma unroll
    for (int i = 0; i < 8; i++) ob[i] = f2bf(e[i] * inv);
    *(short8*)(P + row * 2048 + tid * 8) = ob;
}

// ---------------------------------------------------------------------------
extern "C" void kernel_launch(void* const* d_in, const int* in_sizes, int n_in,
                              void* d_out, int out_size, void* d_ws, size_t ws_size,
                              hipStream_t stream)
{
    const float* enc = (const float*)d_in[0];   // [8,2048,512]
    const float* dec = (const float*)d_in[1];   // [8,2048,512]
    const float* W   = (const float*)d_in[2];   // [512,512]
    float* out = (float*)d_out;                 // [8,2048,512]

    const long BSE = 8l * 2048 * 512;           // 8388608
    const long NW  = 512l * 512;

    char* p = (char*)d_ws;
    auto take = [&](long bytes) { char* r = p; p += (bytes + 255) & ~255l; return r; };
    short* enc_hi = (short*)take(BSE * 2);
    short* enc_lo = (short*)take(BSE * 2);
    short* dec_hi = (short*)take(BSE * 2);
    short* dec_lo = (short*)take(BSE * 2);
    short* ep_hi  = (short*)take(BSE * 2);
    short* ep_lo  = (short*)take(BSE * 2);
    short* enc_t  = (short*)take(BSE * 2);
    short* wt_hi  = (short*)take(NW * 2);
    short* wt_lo  = (short*)take(NW * 2);
    float* logits = (float*)take(8l * 2048 * 2048 * 4);   // total ~253 MB
    // P [8][2048][2048] bf16 = 67.1 MB: aliases enc_hi..dec_lo (4 x 16.78 MB,
    // contiguous, all dead once softmax runs).
    short* Pbuf = enc_hi;
    (void)ws_size; (void)in_sizes; (void)n_in; (void)out_size;

    // one-time: allow 64 KiB dynamic LDS for gemm3_256 (host-side, not a
    // stream op -> graph-capture safe)
    static bool attr_set = false;
    if (!attr_set) {
        (void)hipFuncSetAttribute((const void*)gemm3_256,
                                  hipFuncAttributeMaxDynamicSharedMemorySize,
                                  65536);
        attr_set = true;
    }

    // enc: split + transpose fused (reads enc once)
    split_transpose_kernel<<<dim3(64, 16, 8), 256, 0, stream>>>(
        enc, enc_hi, enc_lo, enc_t);
    split_kernel<<<4096, 256, 0, stream>>>(dec, dec_hi, dec_lo);
    split_w_kernel<<<1024, 256, 0, stream>>>(W, wt_hi, wt_lo);

    // enc_proj = enc @ W  (M=16384, N=512, K=512), 3-term, split bf16 output
    gemm_bt<3, true><<<dim3(4, 128, 1), 256, 64 * 1024, stream>>>(
        enc_hi, enc_lo, wt_hi, wt_lo, nullptr, ep_hi, ep_lo,
        512, 512, 512, 512, 0, 0, 0);

    // logits[b] = dec[b] @ ep[b]^T  (M=2048, N=2048, K=512) x 8, 3-term
    // 256x256 tiles: 8x8 tiles x 8 batches = 512 blocks (XCD-swizzled inside)
    gemm3_256<<<512, 512, 65536, stream>>>(
        dec_hi, dec_lo, ep_hi, ep_lo, logits,
        512, 512, 512, 2048, 2048l * 512, 2048l * 512, 2048l * 2048, 8, 8);

    softmax_kernel<<<16384, 256, 0, stream>>>(logits, Pbuf);

    // out[b] = P[b] @ enc[b]  (M=2048, N=512, K=2048) x 8, plain bf16
    gemm_bt<1, false><<<dim3(4, 16, 8), 256, 32 * 1024, stream>>>(
        Pbuf, nullptr, enc_t, nullptr, out, nullptr, nullptr,
        2048, 2048, 2048, 512, 2048l * 2048, 512l * 2048, 2048l * 512);
}

// Round 6
// 335.177 us; speedup vs baseline: 1.4349x; 1.4349x over previous
//
#include <hip/hip_runtime.h>
#include <cstdint>

// ---------------------------------------------------------------------------
// Attention (Luong general): out = softmax(dec @ (enc@W)^T) @ enc
// B=8, S_enc=S_dec=2048, H=512, fp32 in/out.
//
// bf16 MFMA; split-precision (hi+lo bf16, 3-term) for the two matmuls feeding
// softmax; plain bf16 for PV.
// Round 8: revert round-5 (spill: 297 regs > 256 cap; + the "LDS at 94%"
// theory was a 2x arithmetic error -- 512 blocks = 2 CU-rounds). Real round-4
// bottleneck: each phase serialized {ds_read drain} then {MFMA} across
// lockstepped waves. Fix: pipeline ds_reads ONE PHASE AHEAD -- each phase
// issues next-phase frags (stay outstanding), then MFMAs on last-phase frags;
// reads drain UNDER the MFMA cluster. 5 phases (16/16/16/16/32 MFMA),
// staging spread P0-P3, single vmcnt(0)+barrier at tile boundary.
// ---------------------------------------------------------------------------

#define DEVINL __device__ __forceinline__

typedef __attribute__((ext_vector_type(8))) short short8;
typedef __attribute__((ext_vector_type(4))) float f32x4;

DEVINL short f2bf(float x) {
    union { float f; uint32_t u; } v; v.f = x;
    uint32_t r = v.u + 0x7FFFu + ((v.u >> 16) & 1u);   // RNE
    return (short)(r >> 16);
}
DEVINL float bf2f(short h) {
    union { uint32_t u; float f; } v; v.u = ((uint32_t)(uint16_t)h) << 16;
    return v.f;
}

DEVINL void gload_lds16(const void* g, void* l) {
    __builtin_amdgcn_global_load_lds(
        (const __attribute__((address_space(1))) char*)g,
        (__attribute__((address_space(3))) char*)l, 16, 0, 0);
}

// ---------------------------------------------------------------------------
// split fp32 -> (hi, lo) bf16 arrays.  8 elems/thread, exact-cover grids.
// ---------------------------------------------------------------------------
__global__ __launch_bounds__(256)
void split_kernel(const float* __restrict__ x, short* __restrict__ hi,
                  short* __restrict__ lo)
{
    long i = ((long)blockIdx.x * 256 + threadIdx.x) * 8;
    f32x4 a = *(const f32x4*)(x + i);
    f32x4 b = *(const f32x4*)(x + i + 4);
    short8 h, l;
#pragma unroll
    for (int j = 0; j < 4; j++) {
        short ha = f2bf(a[j]); h[j] = ha;     l[j] = f2bf(a[j] - bf2f(ha));
        short hb = f2bf(b[j]); h[4 + j] = hb; l[4 + j] = f2bf(b[j] - bf2f(hb));
    }
    *(short8*)(hi + i) = h;
    *(short8*)(lo + i) = l;
}

// W[512k][512n] -> Wt_hi/lo[n][k]
__global__ __launch_bounds__(256)
void split_w_kernel(const float* __restrict__ w, short* __restrict__ wth,
                    short* __restrict__ wtl)
{
    int idx = blockIdx.x * 256 + threadIdx.x;   // k*512 + n
    int k = idx >> 9, n = idx & 511;
    float v = w[idx];
    short h = f2bf(v);
    wth[(long)n * 512 + k] = h;
    wtl[(long)n * 512 + k] = f2bf(v - bf2f(h));
}

// Fused: enc[b][s][e] fp32 -> enc_hi/enc_lo [b][s][e] bf16 + enc_t[b][e][s]
// bf16 (PV B-operand).  Reads enc exactly once.
__global__ __launch_bounds__(256)
void split_transpose_kernel(const float* __restrict__ x, short* __restrict__ hi,
                            short* __restrict__ lo, short* __restrict__ xt)
{
    __shared__ short tile[32][33];
    const int b  = blockIdx.z;
    const int s0 = blockIdx.x * 32;
    const int e0 = blockIdx.y * 32;
    const float* px = x + (long)b * 2048 * 512;
    short* ph = hi + (long)b * 2048 * 512;
    short* pl = lo + (long)b * 2048 * 512;
    short* pt = xt + (long)b * 512 * 2048;
    const int tx = threadIdx.x & 31;
    const int ty = threadIdx.x >> 5;   // 0..7
#pragma unroll
    for (int r = 0; r < 32; r += 8) {
        long idx = (long)(s0 + ty + r) * 512 + e0 + tx;
        float v = px[idx];
        short h = f2bf(v);
        ph[idx] = h;
        pl[idx] = f2bf(v - bf2f(h));
        tile[ty + r][tx] = h;
    }
    __syncthreads();
#pragma unroll
    for (int r = 0; r < 32; r += 8)
        pt[(long)(e0 + ty + r) * 2048 + s0 + tx] = tile[tx][ty + r];
}

// ---------------------------------------------------------------------------
// gemm_bt: C[m][n] = sum_k A[m][k]*B[n][k]  (both operands K-contiguous).
// 128x128 tile, BK=32, 4 waves (2x2 of 64x64), 16x16x32 bf16 MFMA.
// (kept for the enc@W projection and the PV matmul)
// ---------------------------------------------------------------------------
template<int NTERMS, bool SPLIT_OUT>
__global__ __launch_bounds__(256, 2)
void gemm_bt(const short* __restrict__ Ah, const short* __restrict__ Al,
             const short* __restrict__ Bh, const short* __restrict__ Bl,
             float* __restrict__ C, short* __restrict__ Ch, short* __restrict__ Cl,
             int K, int lda, int ldb, int ldc,
             long sA, long sB, long sC)
{
    extern __shared__ char smem_raw[];
    constexpr int OPS = (NTERMS == 3) ? 4 : 2;     // operand planes per set
    constexpr int SET = 128 * 32 * OPS;            // shorts per buffer set
    short* smem = (short*)smem_raw;                // 2 sets

    const int tid  = threadIdx.x;
    const int wave = tid >> 6;
    const int lane = tid & 63;
    const int quad = lane >> 4;
    const int l16  = lane & 15;
    const int wm   = (wave >> 1) * 64;
    const int wn   = (wave & 1) * 64;

    const long tile_m = (long)blockIdx.y * 128;
    const long tile_n = (long)blockIdx.x * 128;
    const int  bz     = blockIdx.z;

    const short* pAh = Ah + (long)bz * sA;
    const short* pBh = Bh + (long)bz * sB;
    const short* pAl = (NTERMS == 3) ? (Al + (long)bz * sA) : nullptr;
    const short* pBl = (NTERMS == 3) ? (Bl + (long)bz * sB) : nullptr;

    // staging: thread t -> row t>>2, k-subchunk (t&3)*8; LDS byte off = 16*t
    const int srow = tid >> 2;
    const int skq  = (tid & 3) * 8;
    const int lds_off = srow * 32 + skq;
    const long ga0 = (tile_m + srow) * (long)lda + skq;
    const long gb0 = (tile_n + srow) * (long)ldb + skq;

    auto stage = [&](int k0, int buf) {
        short* s   = smem + buf * SET;
        short* ash = s;
        short* bsh = s + 128 * 32;
        gload_lds16(pAh + ga0 + k0,             ash + lds_off);
        gload_lds16(pAh + ga0 + 64l * lda + k0, ash + lds_off + 64 * 32);
        gload_lds16(pBh + gb0 + k0,             bsh + lds_off);
        gload_lds16(pBh + gb0 + 64l * ldb + k0, bsh + lds_off + 64 * 32);
        if constexpr (NTERMS == 3) {
            short* asl = s + 2 * 128 * 32;
            short* bsl = s + 3 * 128 * 32;
            gload_lds16(pAl + ga0 + k0,             asl + lds_off);
            gload_lds16(pAl + ga0 + 64l * lda + k0, asl + lds_off + 64 * 32);
            gload_lds16(pBl + gb0 + k0,             bsl + lds_off);
            gload_lds16(pBl + gb0 + 64l * ldb + k0, bsl + lds_off + 64 * 32);
        }
    };

    f32x4 acc[4][4] = {};
    stage(0, 0);
    int cur = 0;

    for (int k0 = 0; k0 < K; k0 += 32) {
        __syncthreads();                    // drains vmcnt: stage(cur) done
        if (k0 + 32 < K) stage(k0 + 32, cur ^ 1);   // prefetch next tile

        short* s   = smem + cur * SET;
        short* ash = s;
        short* bsh = s + 128 * 32;
        short* asl = s + 2 * 128 * 32;
        short* bsl = s + 3 * 128 * 32;

        short8 ah[4], bh[4], al[4], bl[4];
#pragma unroll
        for (int i = 0; i < 4; i++) {
            ah[i] = *(const short8*)&ash[(wm + i * 16 + l16) * 32 + quad * 8];
            bh[i] = *(const short8*)&bsh[(wn + i * 16 + l16) * 32 + quad * 8];
            if constexpr (NTERMS == 3) {
                al[i] = *(const short8*)&asl[(wm + i * 16 + l16) * 32 + quad * 8];
                bl[i] = *(const short8*)&bsl[(wn + i * 16 + l16) * 32 + quad * 8];
            }
        }
#pragma unroll
        for (int i = 0; i < 4; i++)
#pragma unroll
            for (int j = 0; j < 4; j++) {
                acc[i][j] = __builtin_amdgcn_mfma_f32_16x16x32_bf16(ah[i], bh[j], acc[i][j], 0, 0, 0);
                if constexpr (NTERMS == 3) {
                    acc[i][j] = __builtin_amdgcn_mfma_f32_16x16x32_bf16(ah[i], bl[j], acc[i][j], 0, 0, 0);
                    acc[i][j] = __builtin_amdgcn_mfma_f32_16x16x32_bf16(al[i], bh[j], acc[i][j], 0, 0, 0);
                }
            }
        cur ^= 1;
    }

    // epilogue: D row = quad*4 + reg, col = lane&15  (m89-verified mapping)
#pragma unroll
    for (int i = 0; i < 4; i++)
#pragma unroll
        for (int j = 0; j < 4; j++) {
            const long row0 = tile_m + wm + i * 16 + quad * 4;
            const long col  = tile_n + wn + j * 16 + l16;
#pragma unroll
            for (int r = 0; r < 4; r++) {
                float v = acc[i][j][r];
                if constexpr (SPLIT_OUT) {
                    long idx = (long)bz * sC + (row0 + r) * (long)ldc + col;
                    short h = f2bf(v);
                    Ch[idx] = h;
                    Cl[idx] = f2bf(v - bf2f(h));
                } else {
                    C[(long)bz * sC + (row0 + r) * (long)ldc + col] = v;
                }
            }
        }
}

// ---------------------------------------------------------------------------
// gemm3_256: C[m][n] = sum_k A[m][k]*B[n][k], 3-term split bf16.
// 256x256 tile, BK=32, 8 waves (2x4 of 128x64), 16x16x32 bf16 MFMA.
// LDS: 2 buffers x 4 planes (Ah,Al,Bh,Bl) x [256][32] shorts = 128 KiB.
//
// Swizzle (verified 0 bank conflicts): element (r,k) of a plane lives at
// 16B-chunk slot (k>>3) ^ ((r>>1)&3); applied by permuting the per-lane
// GLOBAL source chunk (global_load_lds dest stays linear) and XOR-ing the
// ds_read address.
//
// Read-ahead pipelined 5-phase schedule: each phase issues the NEXT phase's
// ds_reads (they stay outstanding and drain UNDER this phase's MFMA cluster;
// the compiler emits counted lgkm waits for the operands, which were issued
// one phase earlier and are already resident):
//   entry: issue ahA,bh (8 rd)
//   P0: issue ahB,bl (8) | stage Ah' | BAR | 16 MFMA ahA.bh
//   P1: issue alA   (4)  | stage Bh' | BAR | 16 MFMA ahB.bh
//   P2: issue alB   (4)  | stage Al' | BAR | 16 MFMA ahA.bl
//   P3:                  | stage Bl' | BAR | 16 MFMA ahB.bl
//   P4: 32 MFMA alA.bh + alB.bh | vmcnt(0) [staged >=2 phases ago, free]
//       | BAR  (alB lgkm-waited by P4 => all buf reads done => overwrite ok)
// Frags: ahA,ahB,bh,bl,alA,alB = 96 VGPR + 128 acc + addr ~ 244 <= 256 cap.
// ---------------------------------------------------------------------------
__global__ __launch_bounds__(512, 2)
void gemm3_256(const short* __restrict__ Ah, const short* __restrict__ Al,
               const short* __restrict__ Bh, const short* __restrict__ Bl,
               float* __restrict__ C,
               int K, int lda, int ldb, int ldc,
               long sA, long sB, long sC, int nbx, int nby)
{
    extern __shared__ char smem_raw[];
    short* smem = (short*)smem_raw;
    constexpr int PL  = 256 * 32;          // 8192 shorts per plane (16 KiB)
    constexpr int SET = 4 * PL;            // shorts per buffer set

    const int t    = threadIdx.x;
    const int wave = t >> 6;
    const int lane = t & 63;
    const int quad = lane >> 4;
    const int l16  = lane & 15;
    const int wm   = (wave >> 2) * 128;    // 2 wave-rows
    const int wn   = (wave & 3) * 64;      // 4 wave-cols
    const int kslot8 = ((quad ^ ((l16 >> 1) & 3)) << 3);

    // bijective XCD swizzle (gridDim.x % 8 == 0): one batch per XCD
    const int nwg = gridDim.x;
    const int wg  = blockIdx.x;
    const int swz = (wg & 7) * (nwg >> 3) + (wg >> 3);
    const int per_b = nbx * nby;
    const int bz  = swz / per_b;
    const int rem = swz - bz * per_b;
    const long tile_m = (long)(rem / nbx) * 256;
    const long tile_n = (long)(rem % nbx) * 256;

    const short* pAh = Ah + (long)bz * sA;
    const short* pAl = Al + (long)bz * sA;
    const short* pBh = Bh + (long)bz * sB;
    const short* pBl = Bl + (long)bz * sB;

    // staging: thread t -> row t>>2 (half0) / +128 (half1), chunk slot t&3
    // holds global chunk (t&3) ^ ((row>>1)&3)  [read-side XOR matches]
    const int srow   = t >> 2;                       // 0..127
    const int schunk = (t & 3) ^ ((t >> 3) & 3);
    const long gA  = (tile_m + srow) * (long)lda + schunk * 8;
    const long gB  = (tile_n + srow) * (long)ldb + schunk * 8;
    const long gA2 = gA + 128l * lda;
    const long gB2 = gB + 128l * ldb;
    const int ld0 = t * 8;                           // shorts, linear dest

    f32x4 acc[8][4] = {};

    // prologue: full tile 0
    {
        short* s = smem;
        gload_lds16(pAh + gA,  s + ld0);
        gload_lds16(pAh + gA2, s + ld0 + 4096);
        gload_lds16(pBh + gB,  s + 2 * PL + ld0);
        gload_lds16(pBh + gB2, s + 2 * PL + ld0 + 4096);
        gload_lds16(pAl + gA,  s + PL + ld0);
        gload_lds16(pAl + gA2, s + PL + ld0 + 4096);
        gload_lds16(pBl + gB,  s + 3 * PL + ld0);
        gload_lds16(pBl + gB2, s + 3 * PL + ld0 + 4096);
    }
    asm volatile("s_waitcnt vmcnt(0)" ::: "memory");
    __builtin_amdgcn_s_barrier();

    const int NT = K >> 5;
    int cur = 0;
#pragma unroll 1
    for (int kt = 0; kt < NT; ++kt) {
        const short* s    = smem + cur * SET;
        short* sn         = smem + (cur ^ 1) * SET;
        const short* ah_p = s;
        const short* al_p = s + PL;
        const short* bh_p = s + 2 * PL;
        const short* bl_p = s + 3 * PL;
        const int  k0n  = (kt + 1) << 5;
        const bool more = (kt + 1 < NT);

        short8 ahA[4], ahB[4], xbh[4], xbl[4], alA[4], alB[4];

        // ---- entry: issue reads for P0 ----
#pragma unroll
        for (int i = 0; i < 4; i++)
            ahA[i] = *(const short8*)&ah_p[(wm + i * 16 + l16) * 32 + kslot8];
#pragma unroll
        for (int j = 0; j < 4; j++)
            xbh[j] = *(const short8*)&bh_p[(wn + j * 16 + l16) * 32 + kslot8];
        __builtin_amdgcn_sched_barrier(0);

        // ---- P0: issue ahB,bl | stage Ah' | 16 MFMA ahA.bh ----
#pragma unroll
        for (int i = 0; i < 4; i++)
            ahB[i] = *(const short8*)&ah_p[(wm + 64 + i * 16 + l16) * 32 + kslot8];
#pragma unroll
        for (int j = 0; j < 4; j++)
            xbl[j] = *(const short8*)&bl_p[(wn + j * 16 + l16) * 32 + kslot8];
        if (more) {
            gload_lds16(pAh + gA  + k0n, sn + ld0);
            gload_lds16(pAh + gA2 + k0n, sn + ld0 + 4096);
        }
        __builtin_amdgcn_sched_barrier(0);
        __builtin_amdgcn_s_barrier();
        __builtin_amdgcn_s_setprio(1);
#pragma unroll
        for (int i = 0; i < 4; i++)
#pragma unroll
            for (int j = 0; j < 4; j++)
                acc[i][j] = __builtin_amdgcn_mfma_f32_16x16x32_bf16(ahA[i], xbh[j], acc[i][j], 0, 0, 0);
        __builtin_amdgcn_s_setprio(0);

        // ---- P1: issue alA | stage Bh' | 16 MFMA ahB.bh ----
#pragma unroll
        for (int i = 0; i < 4; i++)
            alA[i] = *(const short8*)&al_p[(wm + i * 16 + l16) * 32 + kslot8];
        if (more) {
            gload_lds16(pBh + gB  + k0n, sn + 2 * PL + ld0);
            gload_lds16(pBh + gB2 + k0n, sn + 2 * PL + ld0 + 4096);
        }
        __builtin_amdgcn_sched_barrier(0);
        __builtin_amdgcn_s_barrier();
        __builtin_amdgcn_s_setprio(1);
#pragma unroll
        for (int i = 0; i < 4; i++)
#pragma unroll
            for (int j = 0; j < 4; j++)
                acc[4 + i][j] = __builtin_amdgcn_mfma_f32_16x16x32_bf16(ahB[i], xbh[j], acc[4 + i][j], 0, 0, 0);
        __builtin_amdgcn_s_setprio(0);

        // ---- P2: issue alB | stage Al' | 16 MFMA ahA.bl ----
#pragma unroll
        for (int i = 0; i < 4; i++)
            alB[i] = *(const short8*)&al_p[(wm + 64 + i * 16 + l16) * 32 + kslot8];
        if (more) {
            gload_lds16(pAl + gA  + k0n, sn + PL + ld0);
            gload_lds16(pAl + gA2 + k0n, sn + PL + ld0 + 4096);
        }
        __builtin_amdgcn_sched_barrier(0);
        __builtin_amdgcn_s_barrier();
        __builtin_amdgcn_s_setprio(1);
#pragma unroll
        for (int i = 0; i < 4; i++)
#pragma unroll
            for (int j = 0; j < 4; j++)
                acc[i][j] = __builtin_amdgcn_mfma_f32_16x16x32_bf16(ahA[i], xbl[j], acc[i][j], 0, 0, 0);
        __builtin_amdgcn_s_setprio(0);

        // ---- P3: stage Bl' | 16 MFMA ahB.bl ----
        if (more) {
            gload_lds16(pBl + gB  + k0n, sn + 3 * PL + ld0);
            gload_lds16(pBl + gB2 + k0n, sn + 3 * PL + ld0 + 4096);
        }
        __builtin_amdgcn_sched_barrier(0);
        __builtin_amdgcn_s_barrier();
        __builtin_amdgcn_s_setprio(1);
#pragma unroll
        for (int i = 0; i < 4; i++)
#pragma unroll
            for (int j = 0; j < 4; j++)
                acc[4 + i][j] = __builtin_amdgcn_mfma_f32_16x16x32_bf16(ahB[i], xbl[j], acc[4 + i][j], 0, 0, 0);
        __builtin_amdgcn_s_setprio(0);
        __builtin_amdgcn_s_barrier();

        // ---- P4: 32 MFMA alA.bh + alB.bh | boundary drain ----
        __builtin_amdgcn_s_setprio(1);
#pragma unroll
        for (int i = 0; i < 4; i++)
#pragma unroll
            for (int j = 0; j < 4; j++)
                acc[i][j] = __builtin_amdgcn_mfma_f32_16x16x32_bf16(alA[i], xbh[j], acc[i][j], 0, 0, 0);
#pragma unroll
        for (int i = 0; i < 4; i++)
#pragma unroll
            for (int j = 0; j < 4; j++)
                acc[4 + i][j] = __builtin_amdgcn_mfma_f32_16x16x32_bf16(alB[i], xbh[j], acc[4 + i][j], 0, 0, 0);
        __builtin_amdgcn_s_setprio(0);
        // alB consumed above => this wave's buf[cur] reads all complete.
        // staging (issued P0-P3, >=2 phases ago) must land before any wave
        // reads buf[cur^1] or overwrites buf[cur] next tile.
        if (more)
            asm volatile("s_waitcnt vmcnt(0)" ::: "memory");
        __builtin_amdgcn_s_barrier();

        cur ^= 1;
    }

    // epilogue: D row = quad*4 + reg, col = lane&15  (m89-verified mapping)
#pragma unroll
    for (int i = 0; i < 8; i++)
#pragma unroll
        for (int j = 0; j < 4; j++) {
            const long row0 = tile_m + wm + i * 16 + quad * 4;
            const long col  = tile_n + wn + j * 16 + l16;
#pragma unroll
            for (int r = 0; r < 4; r++)
                C[(long)bz * sC + (row0 + r) * (long)ldc + col] = acc[i][j][r];
        }
}

// ---------------------------------------------------------------------------
// Row softmax over 2048 fp32 logits; writes P as contiguous bf16.
// ---------------------------------------------------------------------------
__global__ __launch_bounds__(256)
void softmax_kernel(const float* __restrict__ logits, short* __restrict__ P)
{
    const long row = blockIdx.x;
    const float* p = logits + row * 2048;
    const int tid = threadIdx.x;
    const int lane = tid & 63, wave = tid >> 6;

    f32x4 v0 = *(const f32x4*)(p + tid * 8);
    f32x4 v1 = *(const f32x4*)(p + tid * 8 + 4);

    float m = fmaxf(fmaxf(fmaxf(v0[0], v0[1]), fmaxf(v0[2], v0[3])),
                    fmaxf(fmaxf(v1[0], v1[1]), fmaxf(v1[2], v1[3])));
#pragma unroll
    for (int o = 32; o > 0; o >>= 1) m = fmaxf(m, __shfl_xor(m, o));

    __shared__ float red[8];
    if (lane == 0) red[wave] = m;
    __syncthreads();
    m = fmaxf(fmaxf(red[0], red[1]), fmaxf(red[2], red[3]));

    float e[8];
    float s = 0.f;
#pragma unroll
    for (int i = 0; i < 4; i++) { e[i] = __expf(v0[i] - m); s += e[i]; }
#pragma unroll
    for (int i = 0; i < 4; i++) { e[4 + i] = __expf(v1[i] - m); s += e[4 + i]; }
#pragma unroll
    for (int o = 32; o > 0; o >>= 1) s += __shfl_xor(s, o);
    if (lane == 0) red[4 + wave] = s;
    __syncthreads();
    const float inv = 1.f / (red[4] + red[5] + red[6] + red[7]);

    short8 ob;
#pragma unroll
    for (int i = 0; i < 8; i++) ob[i] = f2bf(e[i] * inv);
    *(short8*)(P + row * 2048 + tid * 8) = ob;
}

// ---------------------------------------------------------------------------
extern "C" void kernel_launch(void* const* d_in, const int* in_sizes, int n_in,
                              void* d_out, int out_size, void* d_ws, size_t ws_size,
                              hipStream_t stream)
{
    const float* enc = (const float*)d_in[0];   // [8,2048,512]
    const float* dec = (const float*)d_in[1];   // [8,2048,512]
    const float* W   = (const float*)d_in[2];   // [512,512]
    float* out = (float*)d_out;                 // [8,2048,512]

    const long BSE = 8l * 2048 * 512;           // 8388608
    const long NW  = 512l * 512;

    char* p = (char*)d_ws;
    auto take = [&](long bytes) { char* r = p; p += (bytes + 255) & ~255l; return r; };
    short* enc_hi = (short*)take(BSE * 2);
    short* enc_lo = (short*)take(BSE * 2);
    short* dec_hi = (short*)take(BSE * 2);
    short* dec_lo = (short*)take(BSE * 2);
    short* ep_hi  = (short*)take(BSE * 2);
    short* ep_lo  = (short*)take(BSE * 2);
    short* enc_t  = (short*)take(BSE * 2);
    short* wt_hi  = (short*)take(NW * 2);
    short* wt_lo  = (short*)take(NW * 2);
    float* logits = (float*)take(8l * 2048 * 2048 * 4);   // total ~253 MB
    // P [8][2048][2048] bf16 = 67.1 MB: aliases enc_hi..dec_lo (4 x 16.78 MB,
    // contiguous, all dead once softmax runs).
    short* Pbuf = enc_hi;
    (void)ws_size; (void)in_sizes; (void)n_in; (void)out_size;

    // one-time: allow 128 KiB dynamic LDS for gemm3_256 (host-side, not a
    // stream op -> graph-capture safe)
    static bool attr_set = false;
    if (!attr_set) {
        (void)hipFuncSetAttribute((const void*)gemm3_256,
                                  hipFuncAttributeMaxDynamicSharedMemorySize,
                                  131072);
        attr_set = true;
    }

    // enc: split + transpose fused (reads enc once)
    split_transpose_kernel<<<dim3(64, 16, 8), 256, 0, stream>>>(
        enc, enc_hi, enc_lo, enc_t);
    split_kernel<<<4096, 256, 0, stream>>>(dec, dec_hi, dec_lo);
    split_w_kernel<<<1024, 256, 0, stream>>>(W, wt_hi, wt_lo);

    // enc_proj = enc @ W  (M=16384, N=512, K=512), 3-term, split bf16 output
    gemm_bt<3, true><<<dim3(4, 128, 1), 256, 64 * 1024, stream>>>(
        enc_hi, enc_lo, wt_hi, wt_lo, nullptr, ep_hi, ep_lo,
        512, 512, 512, 512, 0, 0, 0);

    // logits[b] = dec[b] @ ep[b]^T  (M=2048, N=2048, K=512) x 8, 3-term
    // 256x256 tiles: 8x8 tiles x 8 batches = 512 blocks (XCD-swizzled inside)
    gemm3_256<<<512, 512, 131072, stream>>>(
        dec_hi, dec_lo, ep_hi, ep_lo, logits,
        512, 512, 512, 2048, 2048l * 512, 2048l * 512, 2048l * 2048, 8, 8);

    softmax_kernel<<<16384, 256, 0, stream>>>(logits, Pbuf);

    // out[b] = P[b] @ enc[b]  (M=2048, N=512, K=2048) x 8, plain bf16
    gemm_bt<1, false><<<dim3(4, 16, 8), 256, 32 * 1024, stream>>>(
        Pbuf, nullptr, enc_t, nullptr, out, nullptr, nullptr,
        2048, 2048, 2048, 512, 2048l * 2048, 512l * 2048, 2048l * 512);
}